// Round 1
// baseline (11685.659 us; speedup 1.0000x reference)
//
#include <hip/hip_runtime.h>

typedef unsigned short u16;
typedef __attribute__((ext_vector_type(8))) short bf8;   // 8 x bf16 (4 VGPRs) MFMA operand
typedef __attribute__((ext_vector_type(4))) float f4;    // MFMA accumulator

#define DEVI static __device__ __forceinline__

constexpr int Bb = 128, Tt = 512, Dd = 128, Hh = 256, G4 = 1024;
constexpr int CH  = 64;        // timesteps per chunk
constexpr int NCH = Tt / CH;   // 8 chunks
constexpr int MCH = CH * Bb;   // 8192 GEMM rows per chunk

DEVI u16 f2bf(float f) {
  union { float f; unsigned u; } v; v.f = f;
  unsigned r = v.u + 0x7FFFu + ((v.u >> 16) & 1u);  // RNE
  return (u16)(r >> 16);
}
DEVI float bf2f(u16 b) { union { unsigned u; float f; } v; v.u = ((unsigned)b) << 16; return v.f; }
DEVI float sigm(float x) { return 1.f / (1.f + __expf(-x)); }
DEVI float tanh_f(float x) {
  float e = __expf(-2.f * fabsf(x));
  float t = (1.f - e) / (1.f + e);
  return copysignf(t, x);
}
DEVI f4 mfma16(bf8 a, bf8 b, f4 c) {
  return __builtin_amdgcn_mfma_f32_16x16x32_bf16(a, b, c, 0, 0, 0);
}

// ---------- prep kernels ----------

// X[B,T,D] fp32 -> Xt[T,B,D] as hi/lo bf16 pair (exact-ish split)
__global__ void k_prep_x(const float* __restrict__ X, u16* __restrict__ Xhi, u16* __restrict__ Xlo) {
  size_t idx = (size_t)blockIdx.x * 256 + threadIdx.x;      // (b*T+t)*D + d
  int d = (int)(idx % Dd);
  size_t bt = idx / Dd;
  int b = (int)(bt / Tt), t = (int)(bt % Tt);
  float x = X[idx];
  u16 hi = f2bf(x);
  u16 lo = f2bf(x - bf2f(hi));
  size_t o = ((size_t)t * Bb + b) * Dd + d;
  Xhi[o] = hi; Xlo[o] = lo;
}

// elementwise hi/lo split, layout preserved (used for Wih0, Wih1 in [4H,K] row-major)
__global__ void k_split(const float* __restrict__ W, u16* __restrict__ hi_, u16* __restrict__ lo_) {
  size_t idx = (size_t)blockIdx.x * 256 + threadIdx.x;
  float v = W[idx];
  u16 hi = f2bf(v);
  hi_[idx] = hi;
  lo_[idx] = f2bf(v - bf2f(hi));
}

// Whh[4H,H] -> fragment-linear bf16 W2: index (((jt*8+kt)*64+lane)*8+i)
// holds B[k][col] = Whh[col][k], col = jt*16+(lane&15), k = kt*32+(lane>>4)*8+i
__global__ void k_prep_whh(const float* __restrict__ Whh, u16* __restrict__ W2) {
  int idx = blockIdx.x * 256 + threadIdx.x;           // 4H*H = 262144
  int i = idx & 7, lane = (idx >> 3) & 63, kt = (idx >> 9) & 7, jt = idx >> 12;
  int jp = (jt << 4) + (lane & 15);
  int k  = ((lane >> 4) << 3) + i + (kt << 5);
  W2[idx] = f2bf(Whh[(size_t)jp * Hh + k]);
}

__global__ void k_bias(const float* __restrict__ a, const float* __restrict__ b, float* __restrict__ o) {
  int i = blockIdx.x * 256 + threadIdx.x;
  if (i < G4) o[i] = a[i] + b[i];
}

// ---------- input GEMM: Cout[M,1024] = A[M,K] @ W[1024,K]^T + bias ----------
// A given as hi(/lo) bf16, W as hi+lo bf16.  Split-bf16 passes:
//   ALO=true : ah*bh + ah*bl + al*bh   (A is true fp32 split)
//   ALO=false: ah*bh + ah*bl           (A exactly representable in bf16, e.g. h1)
template <int K, bool ALO>
__global__ void __launch_bounds__(256) k_gemm(
    const u16* __restrict__ Ahi, const u16* __restrict__ Alo,
    const u16* __restrict__ Whi, const u16* __restrict__ Wlo,
    const float* __restrict__ bias, float* __restrict__ Cout) {
  __shared__ u16 AsH[128][32];
  __shared__ u16 AsL[128][32];
  const int tid = threadIdx.x, l = tid & 63;
  const int w = tid >> 6, wm = w >> 1, wn = w & 1;
  const int lrow = l & 15, lk = (l >> 4) << 3;
  const size_t m0 = (size_t)blockIdx.x * 128;
  const int n0 = blockIdx.y * 128;

  f4 acc[4][4];
  size_t colK[4];
#pragma unroll
  for (int ni = 0; ni < 4; ++ni) {
    int col = n0 + wn * 64 + ni * 16 + lrow;
    float bv = bias[col];
    colK[ni] = (size_t)col * K + lk;
#pragma unroll
    for (int mi = 0; mi < 4; ++mi) {
      acc[mi][ni][0] = bv; acc[mi][ni][1] = bv; acc[mi][ni][2] = bv; acc[mi][ni][3] = bv;
    }
  }

  for (int kk = 0; kk < K; kk += 32) {
    __syncthreads();
#pragma unroll
    for (int s = 0; s < 2; ++s) {
      int slot = s * 256 + tid;
      int r = slot >> 2, kg = (slot & 3) << 3;
      *(bf8*)&AsH[r][kg] = *(const bf8*)&Ahi[(m0 + r) * K + kk + kg];
      if constexpr (ALO) *(bf8*)&AsL[r][kg] = *(const bf8*)&Alo[(m0 + r) * K + kk + kg];
    }
    __syncthreads();

    bf8 bh[4], bl[4];
#pragma unroll
    for (int ni = 0; ni < 4; ++ni) {
      bh[ni] = *(const bf8*)&Whi[colK[ni] + kk];
      bl[ni] = *(const bf8*)&Wlo[colK[ni] + kk];
    }
    bf8 ah[4], al[4];
#pragma unroll
    for (int mi = 0; mi < 4; ++mi) {
      ah[mi] = *(const bf8*)&AsH[wm * 64 + mi * 16 + lrow][lk];
      if constexpr (ALO) al[mi] = *(const bf8*)&AsL[wm * 64 + mi * 16 + lrow][lk];
    }
#pragma unroll
    for (int mi = 0; mi < 4; ++mi)
#pragma unroll
      for (int ni = 0; ni < 4; ++ni) {
        acc[mi][ni] = mfma16(ah[mi], bh[ni], acc[mi][ni]);
        acc[mi][ni] = mfma16(ah[mi], bl[ni], acc[mi][ni]);
        if constexpr (ALO) acc[mi][ni] = mfma16(al[mi], bh[ni], acc[mi][ni]);
      }
  }

#pragma unroll
  for (int mi = 0; mi < 4; ++mi)
#pragma unroll
    for (int ni = 0; ni < 4; ++ni)
#pragma unroll
      for (int r = 0; r < 4; ++r)
        Cout[(m0 + wm * 64 + mi * 16 + ((l >> 4) << 2) + r) * G4 + n0 + wn * 64 + ni * 16 + lrow] =
            acc[mi][ni][r];
}

// ---------- recurrence ----------
// 8 blocks x 512 thr; block bg owns batches [16bg,16bg+16), wave w owns hidden j in [32w,32w+32).
// gates[b][j'] = xg[t][b][j'] + sum_k h[b][k]*Whh[j'][k]; c,h kept in VGPRs; h broadcast via LDS.

#define LOADB(DST, JTG) do {                                        \
    const u16* _p = W2 + ((size_t)(JTG) << 12) + (l << 3);          \
    _Pragma("unroll")                                               \
    for (int _kt = 0; _kt < 8; ++_kt)                               \
      DST[_kt] = *(const bf8*)(_p + (_kt << 9));                    \
  } while (0)

#define STAGE(IDX, BUF, OTH) do {                                                \
    if ((IDX) < 7) LOADB(OTH, ((((IDX) + 1) >> 1) << 4) + (w << 1) + (((IDX) + 1) & 1)); \
    _Pragma("unroll")                                                            \
    for (int _k = 0; _k < 8; ++_k)                                               \
      acc[(IDX) >> 1][(IDX) & 1] =                                               \
          mfma16(af[_k], BUF[_k], acc[(IDX) >> 1][(IDX) & 1]);                   \
  } while (0)

#define LOADXG(T) do {                                                             \
    const float* _x = xg + ((size_t)(T) * Bb + b_base + (lg << 2)) * G4            \
                         + (w << 5) + lrow;                                        \
    _Pragma("unroll")                                                              \
    for (int _q = 0; _q < 4; ++_q)                                                 \
      _Pragma("unroll")                                                            \
      for (int _jt = 0; _jt < 2; ++_jt)                                            \
        _Pragma("unroll")                                                          \
        for (int _r = 0; _r < 4; ++_r)                                             \
          xgn[_q][_jt][_r] = _x[(size_t)_r * G4 + (_q << 8) + (_jt << 4)];         \
  } while (0)

__global__ void __launch_bounds__(512) k_recur(
    const float* __restrict__ xg,   // [CH][128][1024] chunk (biases already folded in)
    const u16* __restrict__ W2,     // fragment-linear Whh bf16
    u16* __restrict__ hseq,         // [T][128][256] bf16
    float* __restrict__ cst,        // [128][256] fp32 carry
    int t0) {
  __shared__ u16 hbuf[2][4096];     // [16][256] bf16, granule-XOR swizzled
  const int tid = threadIdx.x, l = tid & 63, w = tid >> 6;
  const int lrow = l & 15, lg = l >> 4;
  const int b_base = blockIdx.x * 16;

  f4 c01[2];
  if (t0 == 0) {
#pragma unroll
    for (int jt = 0; jt < 2; ++jt)
#pragma unroll
      for (int r = 0; r < 4; ++r) c01[jt][r] = 0.f;
    for (int i = tid; i < 4096; i += 512) hbuf[0][i] = 0;
  } else {
    const u16* hp = hseq + ((size_t)(t0 - 1) * Bb + b_base) * Hh;
    int b = tid >> 5, g = tid & 31;   // 512 = 16 rows x 32 granules
    *(bf8*)&hbuf[0][(b << 8) + ((g ^ b) << 3)] = *(const bf8*)&hp[(size_t)b * Hh + (g << 3)];
#pragma unroll
    for (int jt = 0; jt < 2; ++jt)
#pragma unroll
      for (int r = 0; r < 4; ++r)
        c01[jt][r] = cst[(size_t)(b_base + (lg << 2) + r) * Hh + (w << 5) + (jt << 4) + lrow];
  }
  __syncthreads();

  f4 xgn[4][2];
  LOADXG(0);

  int cur = 0;
  for (int t = 0; t < CH; ++t) {
    // A fragments: h[b=lrow][k = kt*32 + lg*8 + i], swizzled granule g^b
    bf8 af[8];
#pragma unroll
    for (int kt = 0; kt < 8; ++kt)
      af[kt] = *(const bf8*)&hbuf[cur][(lrow << 8) + ((((kt << 2) + lg) ^ lrow) << 3)];

    f4 acc[4][2];
#pragma unroll
    for (int q = 0; q < 4; ++q)
#pragma unroll
      for (int jt = 0; jt < 2; ++jt) acc[q][jt] = xgn[q][jt];

    if (t + 1 < CH) LOADXG(t + 1);   // prefetch next step's xg

    bf8 bA[8], bB[8];
    LOADB(bA, (w << 1));             // (q=0,jt=0): jtg = w*2
    STAGE(0, bA, bB); STAGE(1, bB, bA); STAGE(2, bA, bB); STAGE(3, bB, bA);
    STAGE(4, bA, bB); STAGE(5, bB, bA); STAGE(6, bA, bB); STAGE(7, bB, bA);

    float hv[2][4];
#pragma unroll
    for (int jt = 0; jt < 2; ++jt)
#pragma unroll
      for (int r = 0; r < 4; ++r) {
        float gi = sigm(acc[0][jt][r]);
        float gf = sigm(acc[1][jt][r]);
        float gg = tanh_f(acc[2][jt][r]);
        float go = sigm(acc[3][jt][r]);
        float cc = gf * c01[jt][r] + gi * gg;
        c01[jt][r] = cc;
        hv[jt][r] = go * tanh_f(cc);
      }

    int nxt = cur ^ 1;
    u16* hrow = hseq + ((size_t)(t0 + t) * Bb + b_base) * Hh;
#pragma unroll
    for (int jt = 0; jt < 2; ++jt)
#pragma unroll
      for (int r = 0; r < 4; ++r) {
        int b = (lg << 2) + r;
        int j = (w << 5) + (jt << 4) + lrow;
        u16 hb = f2bf(hv[jt][r]);
        hrow[(size_t)b * Hh + j] = hb;
        hbuf[nxt][(b << 8) + (((j >> 3) ^ b) << 3) + (j & 7)] = hb;
      }
    __syncthreads();
    cur = nxt;
  }

#pragma unroll
  for (int jt = 0; jt < 2; ++jt)
#pragma unroll
    for (int r = 0; r < 4; ++r)
      cst[(size_t)(b_base + (lg << 2) + r) * Hh + (w << 5) + (jt << 4) + lrow] = c01[jt][r];
}

#undef LOADB
#undef STAGE
#undef LOADXG

// ---------- final FC: out[b] = h2[T-1,b,:] . Wfc + bfc ----------
__global__ void k_fc(const u16* __restrict__ h2l, const float* __restrict__ Wfc,
                     const float* __restrict__ bfc, float* __restrict__ out) {
  int b = threadIdx.x;
  if (b < Bb) {
    float s = bfc[0];
    for (int j = 0; j < Hh; ++j) s += bf2f(h2l[(size_t)b * Hh + j]) * Wfc[j];
    out[b] = s;
  }
}

// ---------- driver ----------
extern "C" void kernel_launch(void* const* d_in, const int* in_sizes, int n_in,
                              void* d_out, int out_size, void* d_ws, size_t ws_size,
                              hipStream_t stream) {
  const float* X    = (const float*)d_in[0];
  const float* Wih0 = (const float*)d_in[1];
  const float* Whh0 = (const float*)d_in[2];
  const float* bih0 = (const float*)d_in[3];
  const float* bhh0 = (const float*)d_in[4];
  const float* Wih1 = (const float*)d_in[5];
  const float* Whh1 = (const float*)d_in[6];
  const float* bih1 = (const float*)d_in[7];
  const float* bhh1 = (const float*)d_in[8];
  const float* Wfc  = (const float*)d_in[9];
  const float* bfc  = (const float*)d_in[10];

  char* base = (char*)d_ws;
  size_t off = 0;
  auto alloc = [&](size_t bytes) -> char* {
    char* p = base + off;
    off = (off + bytes + 255) & ~(size_t)255;
    return p;
  };

  u16* Xhi = (u16*)alloc((size_t)Bb * Tt * Dd * 2);
  u16* Xlo = (u16*)alloc((size_t)Bb * Tt * Dd * 2);
  u16* W0h = (u16*)alloc((size_t)G4 * Dd * 2);
  u16* W0l = (u16*)alloc((size_t)G4 * Dd * 2);
  u16* W1h = (u16*)alloc((size_t)G4 * Hh * 2);
  u16* W1l = (u16*)alloc((size_t)G4 * Hh * 2);
  u16* W2a = (u16*)alloc((size_t)G4 * Hh * 2);
  u16* W2b = (u16*)alloc((size_t)G4 * Hh * 2);
  float* b0 = (float*)alloc(G4 * 4);
  float* b1 = (float*)alloc(G4 * 4);
  float* xgb = (float*)alloc((size_t)MCH * G4 * 4);     // 33.5 MB chunk buffer
  u16* h1 = (u16*)alloc((size_t)Tt * Bb * Hh * 2);
  u16* h2 = (u16*)alloc((size_t)Tt * Bb * Hh * 2);
  float* cst = (float*)alloc((size_t)Bb * Hh * 4);

  k_prep_x<<<(Bb * Tt * Dd) / 256, 256, 0, stream>>>(X, Xhi, Xlo);
  k_split<<<(G4 * Dd) / 256, 256, 0, stream>>>(Wih0, W0h, W0l);
  k_split<<<(G4 * Hh) / 256, 256, 0, stream>>>(Wih1, W1h, W1l);
  k_prep_whh<<<(G4 * Hh) / 256, 256, 0, stream>>>(Whh0, W2a);
  k_prep_whh<<<(G4 * Hh) / 256, 256, 0, stream>>>(Whh1, W2b);
  k_bias<<<4, 256, 0, stream>>>(bih0, bhh0, b0);
  k_bias<<<4, 256, 0, stream>>>(bih1, bhh1, b1);

  for (int c = 0; c < NCH; ++c) {
    k_gemm<Dd, true><<<dim3(64, 8), 256, 0, stream>>>(
        Xhi + (size_t)c * MCH * Dd, Xlo + (size_t)c * MCH * Dd, W0h, W0l, b0, xgb);
    k_recur<<<8, 512, 0, stream>>>(xgb, W2a, h1, cst, c * CH);
  }
  for (int c = 0; c < NCH; ++c) {
    k_gemm<Hh, false><<<dim3(64, 8), 256, 0, stream>>>(
        h1 + (size_t)c * MCH * Hh, nullptr, W1h, W1l, b1, xgb);
    k_recur<<<8, 512, 0, stream>>>(xgb, W2b, h2, cst, c * CH);
  }
  k_fc<<<1, 128, 0, stream>>>(h2 + (size_t)(Tt - 1) * Bb * Hh, Wfc, bfc, (float*)d_out);

  (void)in_sizes; (void)n_in; (void)out_size; (void)ws_size;
}

// Round 2
// 7176.899 us; speedup vs baseline: 1.6282x; 1.6282x over previous
//
#include <hip/hip_runtime.h>

typedef unsigned short u16;
typedef __attribute__((ext_vector_type(8))) short bf8;   // 8 x bf16 (4 VGPRs) MFMA operand
typedef __attribute__((ext_vector_type(4))) float f4;    // MFMA accumulator

#define DEVI static __device__ __forceinline__

constexpr int Bb = 128, Tt = 512, Dd = 128, Hh = 256, G4 = 1024;
constexpr int CH  = 64;        // timesteps per chunk
constexpr int NCH = Tt / CH;   // 8 chunks
constexpr int MCH = CH * Bb;   // 8192 GEMM rows per chunk

DEVI u16 f2bf(float f) {
  union { float f; unsigned u; } v; v.f = f;
  unsigned r = v.u + 0x7FFFu + ((v.u >> 16) & 1u);  // RNE
  return (u16)(r >> 16);
}
DEVI float bf2f(u16 b) { union { unsigned u; float f; } v; v.u = ((unsigned)b) << 16; return v.f; }
DEVI float sigm(float x) { return 1.f / (1.f + __expf(-x)); }
DEVI float tanh_f(float x) {
  float e = __expf(-2.f * fabsf(x));
  float t = (1.f - e) / (1.f + e);
  return copysignf(t, x);
}
DEVI f4 mfma16(bf8 a, bf8 b, f4 c) {
  return __builtin_amdgcn_mfma_f32_16x16x32_bf16(a, b, c, 0, 0, 0);
}

// ---------- prep kernels ----------

__global__ void k_prep_x(const float* __restrict__ X, u16* __restrict__ Xhi, u16* __restrict__ Xlo) {
  size_t idx = (size_t)blockIdx.x * 256 + threadIdx.x;      // (b*T+t)*D + d
  int d = (int)(idx % Dd);
  size_t bt = idx / Dd;
  int b = (int)(bt / Tt), t = (int)(bt % Tt);
  float x = X[idx];
  u16 hi = f2bf(x);
  u16 lo = f2bf(x - bf2f(hi));
  size_t o = ((size_t)t * Bb + b) * Dd + d;
  Xhi[o] = hi; Xlo[o] = lo;
}

__global__ void k_split(const float* __restrict__ W, u16* __restrict__ hi_, u16* __restrict__ lo_) {
  size_t idx = (size_t)blockIdx.x * 256 + threadIdx.x;
  float v = W[idx];
  u16 hi = f2bf(v);
  hi_[idx] = hi;
  lo_[idx] = f2bf(v - bf2f(hi));
}

// Whh[4H,H] -> fragment-linear bf16 W2: offset jt*4096 + kt*512 + lane*8 + i
// holds B[k][col], col = jt*16+(lane&15), k = kt*32+(lane>>4)*8+i
__global__ void k_prep_whh(const float* __restrict__ Whh, u16* __restrict__ W2) {
  int idx = blockIdx.x * 256 + threadIdx.x;           // 4H*H = 262144
  int i = idx & 7, lane = (idx >> 3) & 63, kt = (idx >> 9) & 7, jt = idx >> 12;
  int jp = (jt << 4) + (lane & 15);
  int k  = ((lane >> 4) << 3) + i + (kt << 5);
  W2[idx] = f2bf(Whh[(size_t)jp * Hh + k]);
}

__global__ void k_bias(const float* __restrict__ a, const float* __restrict__ b, float* __restrict__ o) {
  int i = blockIdx.x * 256 + threadIdx.x;
  if (i < G4) o[i] = a[i] + b[i];
}

// ---------- input GEMM: gates = A[M,K] @ W[1024,K]^T + bias, written in XGF layout ----------
// XGF f4 index: (((t8)*8 + wr)*8 + qq)*64 + lane   where t8 = (m>>4) = bx*8+wm*4+mi,
// wr = (col>>5)&7, qq = (col>>8)*2 + ((col>>4)&1), lane encodes (b&15, col&15), r = b&3.
template <int K, bool ALO>
__global__ void __launch_bounds__(256) k_gemm(
    const u16* __restrict__ Ahi, const u16* __restrict__ Alo,
    const u16* __restrict__ Whi, const u16* __restrict__ Wlo,
    const float* __restrict__ bias, float* __restrict__ Cout) {
  __shared__ u16 AsH[128][32];
  __shared__ u16 AsL[128][32];
  const int tid = threadIdx.x, l = tid & 63;
  const int w = tid >> 6, wm = w >> 1, wn = w & 1;
  const int lrow = l & 15, lk = (l >> 4) << 3;
  const size_t m0 = (size_t)blockIdx.x * 128;
  const int n0 = blockIdx.y * 128;

  f4 acc[4][4];
  size_t colK[4];
#pragma unroll
  for (int ni = 0; ni < 4; ++ni) {
    int col = n0 + wn * 64 + ni * 16 + lrow;
    float bv = bias[col];
    colK[ni] = (size_t)col * K + lk;
#pragma unroll
    for (int mi = 0; mi < 4; ++mi) {
      acc[mi][ni][0] = bv; acc[mi][ni][1] = bv; acc[mi][ni][2] = bv; acc[mi][ni][3] = bv;
    }
  }

  for (int kk = 0; kk < K; kk += 32) {
    __syncthreads();
#pragma unroll
    for (int s = 0; s < 2; ++s) {
      int slot = s * 256 + tid;
      int r = slot >> 2, kg = (slot & 3) << 3;
      *(bf8*)&AsH[r][kg] = *(const bf8*)&Ahi[(m0 + r) * K + kk + kg];
      if constexpr (ALO) *(bf8*)&AsL[r][kg] = *(const bf8*)&Alo[(m0 + r) * K + kk + kg];
    }
    __syncthreads();

    bf8 bh[4], bl[4];
#pragma unroll
    for (int ni = 0; ni < 4; ++ni) {
      bh[ni] = *(const bf8*)&Whi[colK[ni] + kk];
      bl[ni] = *(const bf8*)&Wlo[colK[ni] + kk];
    }
    bf8 ah[4], al[4];
#pragma unroll
    for (int mi = 0; mi < 4; ++mi) {
      ah[mi] = *(const bf8*)&AsH[wm * 64 + mi * 16 + lrow][lk];
      if constexpr (ALO) al[mi] = *(const bf8*)&AsL[wm * 64 + mi * 16 + lrow][lk];
    }
#pragma unroll
    for (int mi = 0; mi < 4; ++mi)
#pragma unroll
      for (int ni = 0; ni < 4; ++ni) {
        acc[mi][ni] = mfma16(ah[mi], bh[ni], acc[mi][ni]);
        acc[mi][ni] = mfma16(ah[mi], bl[ni], acc[mi][ni]);
        if constexpr (ALO) acc[mi][ni] = mfma16(al[mi], bh[ni], acc[mi][ni]);
      }
  }

  // epilogue: XGF layout, one fully-coalesced f4 store per (mi,ni)
  f4* C4 = (f4*)Cout;
  const int by = blockIdx.y;
#pragma unroll
  for (int mi = 0; mi < 4; ++mi) {
    size_t t8 = ((size_t)blockIdx.x * 8 + wm * 4 + mi);
#pragma unroll
    for (int ni = 0; ni < 4; ++ni) {
      int wr = ((by & 1) << 2) + (wn << 1) + (ni >> 1);
      int qq = ((by >> 1) << 1) + (ni & 1);
      C4[((t8 * 8 + wr) * 8 + qq) * 64 + l] = acc[mi][ni];
    }
  }
}

// ---------- recurrence ----------
// 8 blocks x 512 thr; block bg owns batches [16bg,16bg+16), wave w owns hidden j in [32w,32w+32).
// Whh split: kt 0..4 streamed from L2 (dbuf), kt 5 in VGPRs, kt 6..7 in LDS (staged once).
// k-major MFMA: per kt, 8 independent MFMAs into acc[0..7]. One barrier/step (dbuf hb).

#define SLOAD(BUF, KT) { _Pragma("unroll") \
    for (int _q = 0; _q < 8; ++_q) BUF[_q] = *(const bf8*)&W2[wbase[_q] + ((KT) << 9)]; }

#define MF2(B, KT) { _Pragma("unroll") \
    for (int _q = 0; _q < 8; ++_q) acc[_q] = mfma16(af[KT], B[_q], acc[_q]); }

#define LOADXG(T) { const f4* _p = xb + (size_t)(T) * 32768; \
    _Pragma("unroll") for (int _q = 0; _q < 8; ++_q) xgn[_q] = _p[_q << 6]; }

__global__ void __launch_bounds__(512) k_recur(
    const float* __restrict__ xg,   // chunk in XGF layout (biases folded)
    const u16* __restrict__ W2,     // fragment-linear Whh bf16
    u16* __restrict__ hseq,         // [T][128][256] bf16
    float* __restrict__ cst,        // [128][256] fp32 carry
    int t0, int write_h) {
  __shared__ u16 hb[2][4096];       // [16][256] bf16, granule-XOR swizzled, double-buffered
  __shared__ u16 wl[65536];         // 128 KB: W2 kt in {6,7}: [(jt*2+kt6)*512 + lane*8 + i]
  const int tid = threadIdx.x, l = tid & 63, w = tid >> 6;
  const int lrow = l & 15, lg = l >> 4;
  const int bg = blockIdx.x;
  const int b_base = bg << 4;

  // stage W2 kt{6,7} stripes into LDS (once per dispatch)
  for (int s = 0; s < 16; ++s) {
    int flat = (s << 9) + tid;      // bf8 granule id 0..8191
    int gofs = ((flat >> 7) << 12) + ((6 + ((flat >> 6) & 1)) << 9) + ((flat & 63) << 3);
    *(bf8*)&wl[flat << 3] = *(const bf8*)&W2[gofs];
  }

  int wbase[8], wlofs[8];
#pragma unroll
  for (int qq = 0; qq < 8; ++qq) {
    int jtg = ((qq >> 1) << 4) + (w << 1) + (qq & 1);
    wbase[qq] = (jtg << 12) + (l << 3);
    wlofs[qq] = (jtg << 10) + (l << 3);
  }
  bf8 wv[8];
#pragma unroll
  for (int qq = 0; qq < 8; ++qq) wv[qq] = *(const bf8*)&W2[wbase[qq] + (5 << 9)];

  f4 c01[2];
  if (t0 == 0) {
#pragma unroll
    for (int q2 = 0; q2 < 2; ++q2)
#pragma unroll
      for (int r = 0; r < 4; ++r) c01[q2][r] = 0.f;
    for (int i = tid; i < 4096; i += 512) hb[0][i] = 0;
  } else {
    const u16* hp = hseq + ((size_t)(t0 - 1) * Bb + b_base) * Hh;
    int b = tid >> 5, g = tid & 31;
    *(bf8*)&hb[0][(b << 8) + ((g ^ b) << 3)] = *(const bf8*)&hp[b * Hh + (g << 3)];
#pragma unroll
    for (int q2 = 0; q2 < 2; ++q2)
#pragma unroll
      for (int r = 0; r < 4; ++r)
        c01[q2][r] = cst[(size_t)(b_base + (lg << 2) + r) * Hh + (w << 5) + (q2 << 4) + lrow];
  }
  __syncthreads();

  const f4* xb = (const f4*)xg + ((size_t)bg * 8 + w) * 512 + l;
  f4 xgn[8];
  LOADXG(0);

  int cur = 0;
  for (int t = 0; t < CH; ++t) {
    bf8 sb0[8], sb1[8];
    SLOAD(sb0, 0);                               // issue kt0 early

    bf8 af[8];                                   // h[b=lrow][k=kt*32+lg*8+i], swizzled
#pragma unroll
    for (int kt = 0; kt < 8; ++kt)
      af[kt] = *(const bf8*)&hb[cur][(lrow << 8) + ((((kt << 2) + lg) ^ lrow) << 3)];

    f4 acc[8];
#pragma unroll
    for (int qq = 0; qq < 8; ++qq) acc[qq] = xgn[qq];

    SLOAD(sb1, 1);
    MF2(sb0, 0);
    SLOAD(sb0, 2);
    MF2(sb1, 1);
    SLOAD(sb1, 3);
    MF2(sb0, 2);
    SLOAD(sb0, 4);
    MF2(sb1, 3);
    if (t + 1 < CH) LOADXG(t + 1);               // after all stream issues: no vmcnt pollution
    MF2(sb0, 4);
    MF2(wv, 5);
    bf8 lb[8];
#pragma unroll
    for (int qq = 0; qq < 8; ++qq) lb[qq] = *(const bf8*)&wl[wlofs[qq]];
    MF2(lb, 6);
#pragma unroll
    for (int qq = 0; qq < 8; ++qq) lb[qq] = *(const bf8*)&wl[wlofs[qq] + 512];
    MF2(lb, 7);

    float hv[2][4];
#pragma unroll
    for (int q2 = 0; q2 < 2; ++q2)
#pragma unroll
      for (int r = 0; r < 4; ++r) {
        float gi = sigm(acc[0 + q2][r]);
        float gf = sigm(acc[2 + q2][r]);
        float gg = tanh_f(acc[4 + q2][r]);
        float go = sigm(acc[6 + q2][r]);
        float cc = gf * c01[q2][r] + gi * gg;
        c01[q2][r] = cc;
        hv[q2][r] = go * tanh_f(cc);
      }

    int nxt = cur ^ 1;
    const bool st = (write_h != 0) || (t == CH - 1);
    u16* hrow = hseq + ((size_t)(t0 + t) * Bb + b_base) * Hh;
#pragma unroll
    for (int q2 = 0; q2 < 2; ++q2)
#pragma unroll
      for (int r = 0; r < 4; ++r) {
        int b = (lg << 2) + r;
        int j = (w << 5) + (q2 << 4) + lrow;
        u16 hbv = f2bf(hv[q2][r]);
        if (st) hrow[b * Hh + j] = hbv;
        hb[nxt][(b << 8) + (((j >> 3) ^ b) << 3) + (j & 7)] = hbv;
      }
    __syncthreads();
    cur = nxt;
  }

#pragma unroll
  for (int q2 = 0; q2 < 2; ++q2)
#pragma unroll
    for (int r = 0; r < 4; ++r)
      cst[(size_t)(b_base + (lg << 2) + r) * Hh + (w << 5) + (q2 << 4) + lrow] = c01[q2][r];
}

#undef SLOAD
#undef MF2
#undef LOADXG

// ---------- final FC ----------
__global__ void k_fc(const u16* __restrict__ h2l, const float* __restrict__ Wfc,
                     const float* __restrict__ bfc, float* __restrict__ out) {
  int b = threadIdx.x;
  if (b < Bb) {
    float s = bfc[0];
    for (int j = 0; j < Hh; ++j) s += bf2f(h2l[(size_t)b * Hh + j]) * Wfc[j];
    out[b] = s;
  }
}

// ---------- driver ----------
extern "C" void kernel_launch(void* const* d_in, const int* in_sizes, int n_in,
                              void* d_out, int out_size, void* d_ws, size_t ws_size,
                              hipStream_t stream) {
  const float* X    = (const float*)d_in[0];
  const float* Wih0 = (const float*)d_in[1];
  const float* Whh0 = (const float*)d_in[2];
  const float* bih0 = (const float*)d_in[3];
  const float* bhh0 = (const float*)d_in[4];
  const float* Wih1 = (const float*)d_in[5];
  const float* Whh1 = (const float*)d_in[6];
  const float* bih1 = (const float*)d_in[7];
  const float* bhh1 = (const float*)d_in[8];
  const float* Wfc  = (const float*)d_in[9];
  const float* bfc  = (const float*)d_in[10];

  char* base = (char*)d_ws;
  size_t off = 0;
  auto alloc = [&](size_t bytes) -> char* {
    char* p = base + off;
    off = (off + bytes + 255) & ~(size_t)255;
    return p;
  };

  u16* Xhi = (u16*)alloc((size_t)Bb * Tt * Dd * 2);
  u16* Xlo = (u16*)alloc((size_t)Bb * Tt * Dd * 2);
  u16* W0h = (u16*)alloc((size_t)G4 * Dd * 2);
  u16* W0l = (u16*)alloc((size_t)G4 * Dd * 2);
  u16* W1h = (u16*)alloc((size_t)G4 * Hh * 2);
  u16* W1l = (u16*)alloc((size_t)G4 * Hh * 2);
  u16* W2a = (u16*)alloc((size_t)G4 * Hh * 2);
  u16* W2b = (u16*)alloc((size_t)G4 * Hh * 2);
  float* b0 = (float*)alloc(G4 * 4);
  float* b1 = (float*)alloc(G4 * 4);
  float* xgb = (float*)alloc((size_t)MCH * G4 * 4);     // 33.5 MB chunk buffer (XGF layout)
  u16* h1 = (u16*)alloc((size_t)Tt * Bb * Hh * 2);
  u16* h2 = (u16*)alloc((size_t)Tt * Bb * Hh * 2);
  float* cst = (float*)alloc((size_t)Bb * Hh * 4);

  k_prep_x<<<(Bb * Tt * Dd) / 256, 256, 0, stream>>>(X, Xhi, Xlo);
  k_split<<<(G4 * Dd) / 256, 256, 0, stream>>>(Wih0, W0h, W0l);
  k_split<<<(G4 * Hh) / 256, 256, 0, stream>>>(Wih1, W1h, W1l);
  k_prep_whh<<<(G4 * Hh) / 256, 256, 0, stream>>>(Whh0, W2a);
  k_prep_whh<<<(G4 * Hh) / 256, 256, 0, stream>>>(Whh1, W2b);
  k_bias<<<4, 256, 0, stream>>>(bih0, bhh0, b0);
  k_bias<<<4, 256, 0, stream>>>(bih1, bhh1, b1);

  for (int c = 0; c < NCH; ++c) {
    k_gemm<Dd, true><<<dim3(64, 8), 256, 0, stream>>>(
        Xhi + (size_t)c * MCH * Dd, Xlo + (size_t)c * MCH * Dd, W0h, W0l, b0, xgb);
    k_recur<<<8, 512, 0, stream>>>(xgb, W2a, h1, cst, c * CH, 1);
  }
  for (int c = 0; c < NCH; ++c) {
    k_gemm<Hh, false><<<dim3(64, 8), 256, 0, stream>>>(
        h1 + (size_t)c * MCH * Hh, nullptr, W1h, W1l, b1, xgb);
    k_recur<<<8, 512, 0, stream>>>(xgb, W2b, h2, cst, c * CH, 0);
  }
  k_fc<<<1, 128, 0, stream>>>(h2 + (size_t)(Tt - 1) * Bb * Hh, Wfc, bfc, (float*)d_out);

  (void)in_sizes; (void)n_in; (void)out_size; (void)ws_size;
}